// Round 10
// baseline (272.674 us; speedup 1.0000x reference)
//
#include <hip/hip_runtime.h>
#include <hip/hip_cooperative_groups.h>
#include <math.h>

namespace cg = cooperative_groups;

#define NB 8
#define NLQ 1024
#define NLK 1024
#define ND 512
#define NH 8
#define MASKV -1e30f
#define LOG2E 1.44269504088896f
#define SHIFT2 32.0f   // fixed exp2-domain shift (replaces running max)

typedef unsigned short ushort_t;
typedef __attribute__((ext_vector_type(8))) _Float16 f16x8;
typedef __attribute__((ext_vector_type(8))) short bf16x8;
typedef __attribute__((ext_vector_type(16))) float f32x16;

__device__ __forceinline__ ushort_t f2h_bits(float f) {
    union { _Float16 h; ushort_t u; } v; v.h = (_Float16)f;
    return v.u;
}
__device__ __forceinline__ ushort_t f2bf(float f) {
    union { float f; unsigned u; } v; v.f = f;
    unsigned r = v.u + 0x7fffu + ((v.u >> 16) & 1u);
    return (ushort_t)(r >> 16);
}
__device__ __forceinline__ void gload16(const ushort_t* g, ushort_t* l) {
    __builtin_amdgcn_global_load_lds(
        (const __attribute__((address_space(1))) void*)g,
        (__attribute__((address_space(3))) void*)l, 16, 0, 0);
}
// pack bf16(p0) | bf16(p1)<<16, truncating (p >= 0)
__device__ __forceinline__ unsigned pack_bf16_trunc(float p0, float p1) {
    return __builtin_amdgcn_perm(__float_as_uint(p1), __float_as_uint(p0),
                                 0x07060302u);
}

// ---------------- W transpose: W (H,512,64) fp32 -> Wt (H,64,512) fp16
__global__ __launch_bounds__(256) void wsplit_kernel(
    const float* __restrict__ Wq, const float* __restrict__ Wk, const float* __restrict__ Wv,
    ushort_t* __restrict__ oq, ushort_t* __restrict__ ok, ushort_t* __restrict__ ov) {
    __shared__ float T[64][65];
    const int d0 = blockIdx.x * 64;
    const int h  = blockIdx.y;
    const int t  = blockIdx.z;
    const float* W = (t == 0) ? Wq : (t == 1) ? Wk : Wv;
    ushort_t* oh = (t == 0) ? oq : (t == 1) ? ok : ov;
    const int tid = threadIdx.x;
#pragma unroll
    for (int i = 0; i < 4; i++) {
        int r = (tid >> 4) + i * 16;
        int c = (tid & 15) * 4;
        float4 v = *(const float4*)&W[((size_t)h * ND + d0 + r) * 64 + c];
        *(float4*)&T[r][c] = v;
    }
    __syncthreads();
    const int e = tid & 63;
    const int dg = tid >> 6;
    ushort_t hs[16];
#pragma unroll
    for (int dd = 0; dd < 16; dd++) hs[dd] = f2h_bits(T[dg * 16 + dd][e]);
    size_t base = ((size_t)h * 64 + e) * ND + d0 + dg * 16;
#pragma unroll
    for (int c = 0; c < 2; c++) {
        uint4 wh;
        wh.x = (unsigned)hs[8*c+0] | ((unsigned)hs[8*c+1] << 16);
        wh.y = (unsigned)hs[8*c+2] | ((unsigned)hs[8*c+3] << 16);
        wh.z = (unsigned)hs[8*c+4] | ((unsigned)hs[8*c+5] << 16);
        wh.w = (unsigned)hs[8*c+6] | ((unsigned)hs[8*c+7] << 16);
        *(uint4*)&oh[base + 8 * c] = wh;
    }
}

// ---------------- Projection GEMM (R9 structure, unchanged).
// M=24576 (t,b,l), N=512 (h,e), K=512. 128x128 tile, BK=64, 4 waves x 2x2.
// A single-buffered (reg pre-read + no-vmcnt-drain barrier), B dbuf DMA.
// Grid 768 = 256 CUs x 3 blocks, 49.9 KB LDS.
__global__ __launch_bounds__(256, 3) void proj_gemm_kernel(
    const float* __restrict__ Xq, const float* __restrict__ Xk,
    const float* __restrict__ Xv, const ushort_t* __restrict__ Wbase,
    ushort_t* __restrict__ Obase) {
    __shared__ ushort_t S[24960];      // sA(8320) + sB0(8320) + sB1(8320)
    ushort_t* const sA  = S;
    ushort_t* const sB0 = S + 8320;
    ushort_t* const sB1 = S + 16640;

    const int bid   = blockIdx.x;
    const int y     = bid / 192;        // N-tile (2 heads)
    const int mglob = bid % 192;
    const int t  = mglob >> 6;          // tensor 0..2
    const int b  = (mglob >> 3) & 7;
    const int l0 = (mglob & 7) * 128;

    const int tid  = threadIdx.x;
    const int wave = tid >> 6;
    const int lane = tid & 63;
    const int l31  = lane & 31;
    const int hib  = lane >> 5;
    const int wr = wave >> 1, wc = wave & 1;

    const float* Xt = (t == 0) ? Xq : (t == 1) ? Xk : Xv;
    const float* gx = Xt + ((size_t)b * NLQ + l0) * ND;
    const ushort_t* gwt = Wbase + (size_t)t * ((size_t)NH * 64 * ND)
                        + (size_t)y * 128 * ND;
    ushort_t* out = Obase + (size_t)t * ((size_t)NB * NH * NLQ * 64);

    const int srow = lane >> 3;             // row in 8-row group
    const int schk = (lane & 7) ^ srow;     // source chunk swizzle

    float4 ax[4][2];
    auto aload = [&](int d0) {
#pragma unroll
        for (int j = 0; j < 4; j++) {
            int row = (j * 4 + wave) * 8 + srow;
            const float* p = gx + (size_t)row * ND + d0 + schk * 8;
            ax[j][0] = *(const float4*)p;
            ax[j][1] = *(const float4*)(p + 4);
        }
    };
    auto awrite = [&]() {
#pragma unroll
        for (int j = 0; j < 4; j++) {
            int u = j * 4 + wave;
            uint4 hv;
            hv.x = (unsigned)f2h_bits(ax[j][0].x) | ((unsigned)f2h_bits(ax[j][0].y) << 16);
            hv.y = (unsigned)f2h_bits(ax[j][0].z) | ((unsigned)f2h_bits(ax[j][0].w) << 16);
            hv.z = (unsigned)f2h_bits(ax[j][1].x) | ((unsigned)f2h_bits(ax[j][1].y) << 16);
            hv.w = (unsigned)f2h_bits(ax[j][1].z) | ((unsigned)f2h_bits(ax[j][1].w) << 16);
            *(uint4*)(sA + u * 520 + lane * 8) = hv;
        }
    };
    auto bstage = [&](ushort_t* dst, int d0) {
#pragma unroll
        for (int j = 0; j < 4; j++) {
            int u = j * 4 + wave;
            int row = u * 8 + srow;
            gload16(gwt + (size_t)row * ND + d0 + schk * 8, dst + u * 520);
        }
    };

    f32x16 acc00, acc01, acc10, acc11;
#pragma unroll
    for (int i = 0; i < 16; i++) { acc00[i] = 0.f; acc01[i] = 0.f;
                                   acc10[i] = 0.f; acc11[i] = 0.f; }

    const int ga  = wr * 8 + (l31 >> 3);    // A group, mi=0 (mi=1: +4)
    const int gb  = wc * 8 + (l31 >> 3);    // B group, ni=0 (ni=1: +4)
    const int ro  = (l31 & 7) * 64;         // row-in-group offset (ushorts)
    const int swz = l31 & 7;                // read-side chunk swizzle

    // prologue: chunk 0 into sA + sB0
    aload(0);
    awrite();                                // compiler waits vmcnt for ax
    bstage(sB0, 0);
    asm volatile("s_waitcnt vmcnt(0) lgkmcnt(0)" ::: "memory");
    __builtin_amdgcn_sched_barrier(0);
    __builtin_amdgcn_s_barrier();
    __builtin_amdgcn_sched_barrier(0);

    ushort_t* sBc = sB0;
    ushort_t* sBn = sB1;
#pragma unroll
    for (int kc = 0; kc < 8; kc++) {
        if (kc < 7) aload((kc + 1) * 64);   // A global loads span both phases
        f16x8 a0[4], a1[4];
#pragma unroll
        for (int c = 0; c < 4; c++) {
            const int pc = ((2 * c + hib) ^ swz) * 8;
            a0[c] = *(const f16x8*)&sA[ga * 520 + ro + pc];
            a1[c] = *(const f16x8*)&sA[(ga + 4) * 520 + ro + pc];
        }
        asm volatile("s_waitcnt lgkmcnt(0)" ::: "memory");  // reads landed
        __builtin_amdgcn_sched_barrier(0);
        __builtin_amdgcn_s_barrier();                       // barrier1 (no vmcnt drain)
        __builtin_amdgcn_sched_barrier(0);
        if (kc < 7) {
            bstage(sBn, (kc + 1) * 64);
            awrite();
        }
#pragma unroll
        for (int c = 0; c < 4; c++) {
            const int pc = ((2 * c + hib) ^ swz) * 8;
            f16x8 b0 = *(const f16x8*)&sBc[gb * 520 + ro + pc];
            f16x8 b1 = *(const f16x8*)&sBc[(gb + 4) * 520 + ro + pc];
            acc00 = __builtin_amdgcn_mfma_f32_32x32x16_f16(a0[c], b0, acc00, 0, 0, 0);
            acc01 = __builtin_amdgcn_mfma_f32_32x32x16_f16(a0[c], b1, acc01, 0, 0, 0);
            acc10 = __builtin_amdgcn_mfma_f32_32x32x16_f16(a1[c], b0, acc10, 0, 0, 0);
            acc11 = __builtin_amdgcn_mfma_f32_32x32x16_f16(a1[c], b1, acc11, 0, 0, 0);
        }
        if (kc < 7) {
            asm volatile("s_waitcnt vmcnt(0) lgkmcnt(0)" ::: "memory");
            __builtin_amdgcn_sched_barrier(0);
            __builtin_amdgcn_s_barrier();                   // barrier2
            __builtin_amdgcn_sched_barrier(0);
        }
        ushort_t* tmp = sBc; sBc = sBn; sBn = tmp;
    }

    if (t < 2) {
        const float scale = (t == 0) ? LOG2E : 1.f;
#pragma unroll
        for (int mi = 0; mi < 2; mi++) {
#pragma unroll
            for (int ni = 0; ni < 2; ni++) {
                const f32x16& a = (mi == 0) ? (ni == 0 ? acc00 : acc01)
                                            : (ni == 0 ? acc10 : acc11);
                int nglob = y * 128 + wc * 64 + ni * 32 + l31;
                int hh = nglob >> 6, e = nglob & 63;
                size_t obase = (((size_t)b * NH + hh) * NLQ + l0) * 64 + e;
#pragma unroll
                for (int r = 0; r < 16; r++) {
                    int l = wr * 64 + mi * 32 + (r & 3) + 8 * (r >> 2) + 4 * hib;
                    out[obase + (size_t)l * 64] = f2h_bits(a[r] * scale);
                }
            }
        }
    } else {
        __syncthreads();
        ushort_t (*T)[130] = (ushort_t(*)[130])S;
#pragma unroll
        for (int mi = 0; mi < 2; mi++) {
#pragma unroll
            for (int ni = 0; ni < 2; ni++) {
                const f32x16& a = (mi == 0) ? (ni == 0 ? acc00 : acc01)
                                            : (ni == 0 ? acc10 : acc11);
                int n_loc = wc * 64 + ni * 32 + l31;
#pragma unroll
                for (int r = 0; r < 16; r++) {
                    int l = wr * 64 + mi * 32 + (r & 3) + 8 * (r >> 2) + 4 * hib;
                    T[n_loc][l] = f2bf(a[r]);
                }
            }
        }
        __syncthreads();
        const int n_loc = tid >> 1;
        const int half  = tid & 1;
        const int hh = n_loc >> 6, e = n_loc & 63;
        size_t obase = (((size_t)b * NH + y * 2 + hh) * 64 + e) * NLK
                     + l0 + half * 64;
        const ushort_t* src = &T[n_loc][half * 64];
#pragma unroll
        for (int c2 = 0; c2 < 8; c2++)
            *(uint4*)&out[obase + c2 * 8] = *(const uint4*)&src[c2 * 8];
    }
}

// ---------------- Fused MFMA flash attention + LayerNorm (cooperative).
// attn phase identical to R9 (8 waves, QBLK=256, grid 256 = 1 block/CU,
// guaranteed co-resident). After the O-write: threadfence + grid.sync, then
// each block LayerNorms 32 rows of out (math identical to old ln_kernel).
// Saves one dispatch; also surfaces attn+ln as a single measurable dispatch.
__global__ __launch_bounds__(512, 2) void attn_ln_kernel(
    const ushort_t* __restrict__ Qf, const ushort_t* __restrict__ Kf,
    const ushort_t* __restrict__ Vt, const float* __restrict__ maskp,
    float* Op, const float* __restrict__ gamma, const float* __restrict__ beta) {
    __shared__ ushort_t sK[2][4160];
    __shared__ ushort_t sV[2][4160];
    __shared__ float sBias[1024];

    const int idx = blockIdx.x;
    const int bh_i = idx & 63;
    const int qc  = idx >> 6;          // 0..3
    const int b = bh_i >> 3, h = bh_i & 7;
    const size_t bh = (size_t)b * NH + h;

    const int tid  = threadIdx.x;
    const int wave = tid >> 6;         // 0..7
    const int lane = tid & 63;
    const int l31  = lane & 31;
    const int hib  = lane >> 5;
    const int q = qc * 256 + wave * 32 + l31;
    const int sw = l31 & 7;

    // bias = mask ? -SHIFT2 : -1e30  (exp2-domain shift + mask in one constant)
    if (tid < 256) {
        const float* mrow = maskp + ((size_t)b << 10);
        float4 m0 = *(const float4*)&mrow[tid * 4];
        float4 bi;
        bi.x = (m0.x > 0.5f) ? -SHIFT2 : MASKV;
        bi.y = (m0.y > 0.5f) ? -SHIFT2 : MASKV;
        bi.z = (m0.z > 0.5f) ? -SHIFT2 : MASKV;
        bi.w = (m0.w > 0.5f) ? -SHIFT2 : MASKV;
        *(float4*)&sBias[tid * 4] = bi;
    }

    f16x8 qh[4];
    {
        const ushort_t* ph = Qf + (bh * NLQ + q) * 64 + hib * 8;
#pragma unroll
        for (int c = 0; c < 4; c++) qh[c] = *(const f16x8*)(ph + c * 16);
    }

    const int srow = lane >> 3;
    const int schk = (lane & 7) ^ srow;

    // K rows permuted (storage row s holds key swap23(s)); V natural; group-padded
    auto stage = [&](int buf, int k0) {
#pragma unroll
        for (int n = 0; n < 2; n++) {
            int u = wave + n * 8;           // 0..15, uniform per wave
            if (u < 8) {
                int row = u * 8 + srow;
                int key = (row & ~12) | ((row & 4) << 1) | ((row & 8) >> 1);
                gload16(Kf + ((bh << 10) + k0 + key) * 64 + schk * 8,
                        sK[buf] + u * 520);
            } else {
                int u8 = u - 8;
                int row = u8 * 8 + srow;
                gload16(Vt + ((bh << 6) + row) * NLK + k0 + schk * 8,
                        sV[buf] + u8 * 520);
            }
        }
    };

    f32x16 O0, O1;
#pragma unroll
    for (int i = 0; i < 16; i++) { O0[i] = 0.f; O1[i] = 0.f; }
    float lrun = 0.f;

    const int rp0 = (l31 >> 3) * 520 + (l31 & 7) * 64;   // rows 0..31
    const int rp1 = rp0 + 4 * 520;                        // rows 32..63

    stage(0, 0);
    __syncthreads();
    int cur = 0;

    for (int t = 0; t < 16; t++) {
        const int k0 = t << 6;
        if (t < 15) stage(cur ^ 1, k0 + 64);

        f32x16 S0, S1;
#pragma unroll
        for (int g = 0; g < 4; g++) {
            const int kb = k0 + 16 * (g >> 1) + 8 * hib + 4 * (g & 1);
            float4 b0 = *(const float4*)&sBias[kb];
            float4 b1 = *(const float4*)&sBias[kb + 32];
            S0[4 * g + 0] = b0.x; S0[4 * g + 1] = b0.y;
            S0[4 * g + 2] = b0.z; S0[4 * g + 3] = b0.w;
            S1[4 * g + 0] = b1.x; S1[4 * g + 1] = b1.y;
            S1[4 * g + 2] = b1.z; S1[4 * g + 3] = b1.w;
        }
#pragma unroll
        for (int c = 0; c < 4; c++) {
            const int pc = ((2 * c + hib) ^ sw) * 8;
            f16x8 a0 = *(const f16x8*)&sK[cur][rp0 + pc];
            f16x8 a1 = *(const f16x8*)&sK[cur][rp1 + pc];
            S0 = __builtin_amdgcn_mfma_f32_32x32x16_f16(a0, qh[c], S0, 0, 0, 0);
            S1 = __builtin_amdgcn_mfma_f32_32x32x16_f16(a1, qh[c], S1, 0, 0, 0);
        }

        unsigned pq[8][2];
#pragma unroll
        for (int g = 0; g < 8; g++) {
            float p0, p1, p2, p3;
            if (g < 4) {
                p0 = __builtin_amdgcn_exp2f(S0[4*g+0]);
                p1 = __builtin_amdgcn_exp2f(S0[4*g+1]);
                p2 = __builtin_amdgcn_exp2f(S0[4*g+2]);
                p3 = __builtin_amdgcn_exp2f(S0[4*g+3]);
            } else {
                p0 = __builtin_amdgcn_exp2f(S1[4*(g-4)+0]);
                p1 = __builtin_amdgcn_exp2f(S1[4*(g-4)+1]);
                p2 = __builtin_amdgcn_exp2f(S1[4*(g-4)+2]);
                p3 = __builtin_amdgcn_exp2f(S1[4*(g-4)+3]);
            }
            lrun += (p0 + p1) + (p2 + p3);
            pq[g][0] = pack_bf16_trunc(p0, p1);
            pq[g][1] = pack_bf16_trunc(p2, p3);
        }

#pragma unroll
        for (int c = 0; c < 4; c++) {
            union { unsigned u[4]; bf16x8 v; } pf;
            pf.u[0] = pq[2 * c][0];     pf.u[1] = pq[2 * c][1];
            pf.u[2] = pq[2 * c + 1][0]; pf.u[3] = pq[2 * c + 1][1];
            const int pc = ((2 * c + hib) ^ sw) * 8;
            bf16x8 v0 = *(const bf16x8*)&sV[cur][rp0 + pc];
            bf16x8 v1 = *(const bf16x8*)&sV[cur][rp1 + pc];
            O0 = __builtin_amdgcn_mfma_f32_32x32x16_bf16(v0, pf.v, O0, 0, 0, 0);
            O1 = __builtin_amdgcn_mfma_f32_32x32x16_bf16(v1, pf.v, O1, 0, 0, 0);
        }
        __syncthreads();
        cur ^= 1;
    }

    lrun += __shfl_xor(lrun, 32);     // other key-half lives in lane^32
    const float linv = 1.f / lrun;
    float* obase = Op + ((size_t)(b * NLQ + q)) * (NH * 64) + h * 64;
#pragma unroll
    for (int me = 0; me < 2; me++) {
#pragma unroll
        for (int g = 0; g < 4; g++) {
            int e0 = me * 32 + 8 * g + 4 * hib;
            float4 o;
            if (me == 0) {
                o.x = O0[4 * g + 0] * linv; o.y = O0[4 * g + 1] * linv;
                o.z = O0[4 * g + 2] * linv; o.w = O0[4 * g + 3] * linv;
            } else {
                o.x = O1[4 * g + 0] * linv; o.y = O1[4 * g + 1] * linv;
                o.z = O1[4 * g + 2] * linv; o.w = O1[4 * g + 3] * linv;
            }
            *(float4*)&obase[e0] = o;
        }
    }

    // ---- LayerNorm phase: all attn writes visible after device fence + grid sync
    __threadfence();
    cg::this_grid().sync();

    const float g = gamma[0], be = beta[0];
#pragma unroll
    for (int i = 0; i < 4; i++) {
        int row = idx * 32 + i * 8 + wave;      // 256 blocks x 32 rows = 8192
        float* x = &Op[(size_t)row * 512];
        float4 v0 = *(const float4*)&x[lane * 8];
        float4 v1 = *(const float4*)&x[lane * 8 + 4];
        float sum = v0.x + v0.y + v0.z + v0.w + v1.x + v1.y + v1.z + v1.w;
        float sq = v0.x * v0.x + v0.y * v0.y + v0.z * v0.z + v0.w * v0.w
                 + v1.x * v1.x + v1.y * v1.y + v1.z * v1.z + v1.w * v1.w;
#pragma unroll
        for (int off = 32; off > 0; off >>= 1) {
            sum += __shfl_down(sum, off);
            sq  += __shfl_down(sq, off);
        }
        sum = __shfl(sum, 0);
        sq  = __shfl(sq, 0);
        const float mean = sum * (1.f / 512.f);
        const float var = sq * (1.f / 512.f) - mean * mean;
        const float rstd = rsqrtf(var + 1e-14f);
        float4 r0, r1;
        r0.x = (v0.x - mean) * rstd * g + be;  r0.y = (v0.y - mean) * rstd * g + be;
        r0.z = (v0.z - mean) * rstd * g + be;  r0.w = (v0.w - mean) * rstd * g + be;
        r1.x = (v1.x - mean) * rstd * g + be;  r1.y = (v1.y - mean) * rstd * g + be;
        r1.z = (v1.z - mean) * rstd * g + be;  r1.w = (v1.w - mean) * rstd * g + be;
        *(float4*)&x[lane * 8] = r0;
        *(float4*)&x[lane * 8 + 4] = r1;
    }
}

extern "C" void kernel_launch(void* const* d_in, const int* in_sizes, int n_in,
                              void* d_out, int out_size, void* d_ws, size_t ws_size,
                              hipStream_t stream) {
    const float* query = (const float*)d_in[0];
    const float* key_t = (const float*)d_in[1];
    const float* value = (const float*)d_in[2];
    const float* mask  = (const float*)d_in[3];
    const float* Wq    = (const float*)d_in[4];
    const float* Wk    = (const float*)d_in[5];
    const float* Wv    = (const float*)d_in[6];
    const float* gamma = (const float*)d_in[7];
    const float* beta  = (const float*)d_in[8];
    float* out = (float*)d_out;

    const size_t A = (size_t)NB * NLQ * ND;        // 4,194,304 (= per-tensor size)
    const size_t WS = (size_t)NH * 64 * ND;        // 262,144
    ushort_t* Qf = (ushort_t*)d_ws;                // fp16 (b,h,l,64), *log2e
    ushort_t* Kf = Qf + A;                          // fp16 (b,h,l,64)
    ushort_t* Vt = Qf + 2 * A;                      // bf16 (b,h,e,l)
    ushort_t* Wt = Qf + 3 * A;                      // fp16 Wt, 3 tensors contiguous

    wsplit_kernel<<<dim3(ND / 64, NH, 3), 256, 0, stream>>>(
        Wq, Wk, Wv, Wt, Wt + WS, Wt + 2 * WS);

    proj_gemm_kernel<<<768, 256, 0, stream>>>(
        query, key_t, value, Wt, Qf);

    {
        void* args[] = {(void*)&Qf, (void*)&Kf, (void*)&Vt, (void*)&mask,
                        (void*)&out, (void*)&gamma, (void*)&beta};
        hipLaunchCooperativeKernel((const void*)attn_ln_kernel,
                                   dim3(256), dim3(512), args, 0, stream);
    }
}

// Round 11
// 157.804 us; speedup vs baseline: 1.7279x; 1.7279x over previous
//
#include <hip/hip_runtime.h>
#include <math.h>

#define NB 8
#define NLQ 1024
#define NLK 1024
#define ND 512
#define NH 8
#define MASKV -1e30f
#define LOG2E 1.44269504088896f
#define SHIFT2 32.0f   // fixed exp2-domain shift (replaces running max)

typedef unsigned short ushort_t;
typedef __attribute__((ext_vector_type(8))) _Float16 f16x8;
typedef __attribute__((ext_vector_type(8))) short bf16x8;
typedef __attribute__((ext_vector_type(16))) float f32x16;

__device__ __forceinline__ ushort_t f2h_bits(float f) {
    union { _Float16 h; ushort_t u; } v; v.h = (_Float16)f;
    return v.u;
}
__device__ __forceinline__ ushort_t f2bf(float f) {
    union { float f; unsigned u; } v; v.f = f;
    unsigned r = v.u + 0x7fffu + ((v.u >> 16) & 1u);
    return (ushort_t)(r >> 16);
}
__device__ __forceinline__ void gload16(const ushort_t* g, ushort_t* l) {
    __builtin_amdgcn_global_load_lds(
        (const __attribute__((address_space(1))) void*)g,
        (__attribute__((address_space(3))) void*)l, 16, 0, 0);
}
// pack bf16(p0) | bf16(p1)<<16, truncating (p >= 0)
__device__ __forceinline__ unsigned pack_bf16_trunc(float p0, float p1) {
    return __builtin_amdgcn_perm(__float_as_uint(p1), __float_as_uint(p0),
                                 0x07060302u);
}

// ---------------- W transpose: W (H,512,64) fp32 -> Wt (H,64,512) fp16
__global__ __launch_bounds__(256) void wsplit_kernel(
    const float* __restrict__ Wq, const float* __restrict__ Wk, const float* __restrict__ Wv,
    ushort_t* __restrict__ oq, ushort_t* __restrict__ ok, ushort_t* __restrict__ ov) {
    __shared__ float T[64][65];
    const int d0 = blockIdx.x * 64;
    const int h  = blockIdx.y;
    const int t  = blockIdx.z;
    const float* W = (t == 0) ? Wq : (t == 1) ? Wk : Wv;
    ushort_t* oh = (t == 0) ? oq : (t == 1) ? ok : ov;
    const int tid = threadIdx.x;
#pragma unroll
    for (int i = 0; i < 4; i++) {
        int r = (tid >> 4) + i * 16;
        int c = (tid & 15) * 4;
        float4 v = *(const float4*)&W[((size_t)h * ND + d0 + r) * 64 + c];
        *(float4*)&T[r][c] = v;
    }
    __syncthreads();
    const int e = tid & 63;
    const int dg = tid >> 6;
    ushort_t hs[16];
#pragma unroll
    for (int dd = 0; dd < 16; dd++) hs[dd] = f2h_bits(T[dg * 16 + dd][e]);
    size_t base = ((size_t)h * 64 + e) * ND + d0 + dg * 16;
#pragma unroll
    for (int c = 0; c < 2; c++) {
        uint4 wh;
        wh.x = (unsigned)hs[8*c+0] | ((unsigned)hs[8*c+1] << 16);
        wh.y = (unsigned)hs[8*c+2] | ((unsigned)hs[8*c+3] << 16);
        wh.z = (unsigned)hs[8*c+4] | ((unsigned)hs[8*c+5] << 16);
        wh.w = (unsigned)hs[8*c+6] | ((unsigned)hs[8*c+7] << 16);
        *(uint4*)&oh[base + 8 * c] = wh;
    }
}

// ---------------- Projection GEMM (R9 structure, unchanged — best measured).
// M=24576 (t,b,l), N=512 (h,e), K=512. 128x128 tile, BK=64, 4 waves x 2x2.
// A single-buffered (reg pre-read + no-vmcnt-drain barrier), B dbuf DMA.
// Grid 768 = 256 CUs x 3 blocks, 49.9 KB LDS.
__global__ __launch_bounds__(256, 3) void proj_gemm_kernel(
    const float* __restrict__ Xq, const float* __restrict__ Xk,
    const float* __restrict__ Xv, const ushort_t* __restrict__ Wbase,
    ushort_t* __restrict__ Obase) {
    __shared__ ushort_t S[24960];      // sA(8320) + sB0(8320) + sB1(8320)
    ushort_t* const sA  = S;
    ushort_t* const sB0 = S + 8320;
    ushort_t* const sB1 = S + 16640;

    const int bid   = blockIdx.x;
    const int y     = bid / 192;        // N-tile (2 heads)
    const int mglob = bid % 192;
    const int t  = mglob >> 6;          // tensor 0..2
    const int b  = (mglob >> 3) & 7;
    const int l0 = (mglob & 7) * 128;

    const int tid  = threadIdx.x;
    const int wave = tid >> 6;
    const int lane = tid & 63;
    const int l31  = lane & 31;
    const int hib  = lane >> 5;
    const int wr = wave >> 1, wc = wave & 1;

    const float* Xt = (t == 0) ? Xq : (t == 1) ? Xk : Xv;
    const float* gx = Xt + ((size_t)b * NLQ + l0) * ND;
    const ushort_t* gwt = Wbase + (size_t)t * ((size_t)NH * 64 * ND)
                        + (size_t)y * 128 * ND;
    ushort_t* out = Obase + (size_t)t * ((size_t)NB * NH * NLQ * 64);

    const int srow = lane >> 3;             // row in 8-row group
    const int schk = (lane & 7) ^ srow;     // source chunk swizzle

    float4 ax[4][2];
    auto aload = [&](int d0) {
#pragma unroll
        for (int j = 0; j < 4; j++) {
            int row = (j * 4 + wave) * 8 + srow;
            const float* p = gx + (size_t)row * ND + d0 + schk * 8;
            ax[j][0] = *(const float4*)p;
            ax[j][1] = *(const float4*)(p + 4);
        }
    };
    auto awrite = [&]() {
#pragma unroll
        for (int j = 0; j < 4; j++) {
            int u = j * 4 + wave;
            uint4 hv;
            hv.x = (unsigned)f2h_bits(ax[j][0].x) | ((unsigned)f2h_bits(ax[j][0].y) << 16);
            hv.y = (unsigned)f2h_bits(ax[j][0].z) | ((unsigned)f2h_bits(ax[j][0].w) << 16);
            hv.z = (unsigned)f2h_bits(ax[j][1].x) | ((unsigned)f2h_bits(ax[j][1].y) << 16);
            hv.w = (unsigned)f2h_bits(ax[j][1].z) | ((unsigned)f2h_bits(ax[j][1].w) << 16);
            *(uint4*)(sA + u * 520 + lane * 8) = hv;
        }
    };
    auto bstage = [&](ushort_t* dst, int d0) {
#pragma unroll
        for (int j = 0; j < 4; j++) {
            int u = j * 4 + wave;
            int row = u * 8 + srow;
            gload16(gwt + (size_t)row * ND + d0 + schk * 8, dst + u * 520);
        }
    };

    f32x16 acc00, acc01, acc10, acc11;
#pragma unroll
    for (int i = 0; i < 16; i++) { acc00[i] = 0.f; acc01[i] = 0.f;
                                   acc10[i] = 0.f; acc11[i] = 0.f; }

    const int ga  = wr * 8 + (l31 >> 3);    // A group, mi=0 (mi=1: +4)
    const int gb  = wc * 8 + (l31 >> 3);    // B group, ni=0 (ni=1: +4)
    const int ro  = (l31 & 7) * 64;         // row-in-group offset (ushorts)
    const int swz = l31 & 7;                // read-side chunk swizzle

    // prologue: chunk 0 into sA + sB0
    aload(0);
    awrite();                                // compiler waits vmcnt for ax
    bstage(sB0, 0);
    asm volatile("s_waitcnt vmcnt(0) lgkmcnt(0)" ::: "memory");
    __builtin_amdgcn_sched_barrier(0);
    __builtin_amdgcn_s_barrier();
    __builtin_amdgcn_sched_barrier(0);

    ushort_t* sBc = sB0;
    ushort_t* sBn = sB1;
#pragma unroll
    for (int kc = 0; kc < 8; kc++) {
        if (kc < 7) aload((kc + 1) * 64);   // A global loads span both phases
        f16x8 a0[4], a1[4];
#pragma unroll
        for (int c = 0; c < 4; c++) {
            const int pc = ((2 * c + hib) ^ swz) * 8;
            a0[c] = *(const f16x8*)&sA[ga * 520 + ro + pc];
            a1[c] = *(const f16x8*)&sA[(ga + 4) * 520 + ro + pc];
        }
        asm volatile("s_waitcnt lgkmcnt(0)" ::: "memory");  // reads landed
        __builtin_amdgcn_sched_barrier(0);
        __builtin_amdgcn_s_barrier();                       // barrier1 (no vmcnt drain)
        __builtin_amdgcn_sched_barrier(0);
        if (kc < 7) {
            bstage(sBn, (kc + 1) * 64);
            awrite();
        }
#pragma unroll
        for (int c = 0; c < 4; c++) {
            const int pc = ((2 * c + hib) ^ swz) * 8;
            f16x8 b0 = *(const f16x8*)&sBc[gb * 520 + ro + pc];
            f16x8 b1 = *(const f16x8*)&sBc[(gb + 4) * 520 + ro + pc];
            acc00 = __builtin_amdgcn_mfma_f32_32x32x16_f16(a0[c], b0, acc00, 0, 0, 0);
            acc01 = __builtin_amdgcn_mfma_f32_32x32x16_f16(a0[c], b1, acc01, 0, 0, 0);
            acc10 = __builtin_amdgcn_mfma_f32_32x32x16_f16(a1[c], b0, acc10, 0, 0, 0);
            acc11 = __builtin_amdgcn_mfma_f32_32x32x16_f16(a1[c], b1, acc11, 0, 0, 0);
        }
        if (kc < 7) {
            asm volatile("s_waitcnt vmcnt(0) lgkmcnt(0)" ::: "memory");
            __builtin_amdgcn_sched_barrier(0);
            __builtin_amdgcn_s_barrier();                   // barrier2
            __builtin_amdgcn_sched_barrier(0);
        }
        ushort_t* tmp = sBc; sBc = sBn; sBn = tmp;
    }

    if (t < 2) {
        const float scale = (t == 0) ? LOG2E : 1.f;
#pragma unroll
        for (int mi = 0; mi < 2; mi++) {
#pragma unroll
            for (int ni = 0; ni < 2; ni++) {
                const f32x16& a = (mi == 0) ? (ni == 0 ? acc00 : acc01)
                                            : (ni == 0 ? acc10 : acc11);
                int nglob = y * 128 + wc * 64 + ni * 32 + l31;
                int hh = nglob >> 6, e = nglob & 63;
                size_t obase = (((size_t)b * NH + hh) * NLQ + l0) * 64 + e;
#pragma unroll
                for (int r = 0; r < 16; r++) {
                    int l = wr * 64 + mi * 32 + (r & 3) + 8 * (r >> 2) + 4 * hib;
                    out[obase + (size_t)l * 64] = f2h_bits(a[r] * scale);
                }
            }
        }
    } else {
        __syncthreads();
        ushort_t (*T)[130] = (ushort_t(*)[130])S;
#pragma unroll
        for (int mi = 0; mi < 2; mi++) {
#pragma unroll
            for (int ni = 0; ni < 2; ni++) {
                const f32x16& a = (mi == 0) ? (ni == 0 ? acc00 : acc01)
                                            : (ni == 0 ? acc10 : acc11);
                int n_loc = wc * 64 + ni * 32 + l31;
#pragma unroll
                for (int r = 0; r < 16; r++) {
                    int l = wr * 64 + mi * 32 + (r & 3) + 8 * (r >> 2) + 4 * hib;
                    T[n_loc][l] = f2bf(a[r]);
                }
            }
        }
        __syncthreads();
        const int n_loc = tid >> 1;
        const int half  = tid & 1;
        const int hh = n_loc >> 6, e = n_loc & 63;
        size_t obase = (((size_t)b * NH + y * 2 + hh) * 64 + e) * NLK
                     + l0 + half * 64;
        const ushort_t* src = &T[n_loc][half * 64];
#pragma unroll
        for (int c2 = 0; c2 < 8; c2++)
            *(uint4*)&out[obase + c2 * 8] = *(const uint4*)&src[c2 * 8];
    }
}

// ---------------- MFMA flash attention (R9 + T5 setprio around MFMA clusters).
// fp16 QK^T, fixed-shift exp2 softmax, bf16 PV. 512 threads (8 waves, 256 q),
// grid 256 (idx&63 = bh for XCD locality). 8 waves share one staged K/V tile.
__global__ __launch_bounds__(512, 2) void attn_kernel(
    const ushort_t* __restrict__ Qf, const ushort_t* __restrict__ Kf,
    const ushort_t* __restrict__ Vt, const float* __restrict__ maskp,
    float* __restrict__ Op) {
    __shared__ ushort_t sK[2][4160];
    __shared__ ushort_t sV[2][4160];
    __shared__ float sBias[1024];

    const int idx = blockIdx.x;
    const int bh_i = idx & 63;
    const int qc  = idx >> 6;          // 0..3
    const int b = bh_i >> 3, h = bh_i & 7;
    const size_t bh = (size_t)b * NH + h;

    const int tid  = threadIdx.x;
    const int wave = tid >> 6;         // 0..7
    const int lane = tid & 63;
    const int l31  = lane & 31;
    const int hib  = lane >> 5;
    const int q = qc * 256 + wave * 32 + l31;
    const int sw = l31 & 7;

    // bias = mask ? -SHIFT2 : -1e30  (exp2-domain shift + mask in one constant)
    if (tid < 256) {
        const float* mrow = maskp + ((size_t)b << 10);
        float4 m0 = *(const float4*)&mrow[tid * 4];
        float4 bi;
        bi.x = (m0.x > 0.5f) ? -SHIFT2 : MASKV;
        bi.y = (m0.y > 0.5f) ? -SHIFT2 : MASKV;
        bi.z = (m0.z > 0.5f) ? -SHIFT2 : MASKV;
        bi.w = (m0.w > 0.5f) ? -SHIFT2 : MASKV;
        *(float4*)&sBias[tid * 4] = bi;
    }

    f16x8 qh[4];
    {
        const ushort_t* ph = Qf + (bh * NLQ + q) * 64 + hib * 8;
#pragma unroll
        for (int c = 0; c < 4; c++) qh[c] = *(const f16x8*)(ph + c * 16);
    }

    const int srow = lane >> 3;
    const int schk = (lane & 7) ^ srow;

    // K rows permuted (storage row s holds key swap23(s)); V natural; group-padded
    auto stage = [&](int buf, int k0) {
#pragma unroll
        for (int n = 0; n < 2; n++) {
            int u = wave + n * 8;           // 0..15, uniform per wave
            if (u < 8) {
                int row = u * 8 + srow;
                int key = (row & ~12) | ((row & 4) << 1) | ((row & 8) >> 1);
                gload16(Kf + ((bh << 10) + k0 + key) * 64 + schk * 8,
                        sK[buf] + u * 520);
            } else {
                int u8 = u - 8;
                int row = u8 * 8 + srow;
                gload16(Vt + ((bh << 6) + row) * NLK + k0 + schk * 8,
                        sV[buf] + u8 * 520);
            }
        }
    };

    f32x16 O0, O1;
#pragma unroll
    for (int i = 0; i < 16; i++) { O0[i] = 0.f; O1[i] = 0.f; }
    float lrun = 0.f;

    const int rp0 = (l31 >> 3) * 520 + (l31 & 7) * 64;   // rows 0..31
    const int rp1 = rp0 + 4 * 520;                        // rows 32..63

    stage(0, 0);
    __syncthreads();
    int cur = 0;

    for (int t = 0; t < 16; t++) {
        const int k0 = t << 6;
        if (t < 15) stage(cur ^ 1, k0 + 64);

        // S init = bias (C-operand); quad g of half s holds keys
        // k0 + 32s + 16(g>>1) + 8hib + 4(g&1) + {0..3}
        f32x16 S0, S1;
#pragma unroll
        for (int g = 0; g < 4; g++) {
            const int kb = k0 + 16 * (g >> 1) + 8 * hib + 4 * (g & 1);
            float4 b0 = *(const float4*)&sBias[kb];
            float4 b1 = *(const float4*)&sBias[kb + 32];
            S0[4 * g + 0] = b0.x; S0[4 * g + 1] = b0.y;
            S0[4 * g + 2] = b0.z; S0[4 * g + 3] = b0.w;
            S1[4 * g + 0] = b1.x; S1[4 * g + 1] = b1.y;
            S1[4 * g + 2] = b1.z; S1[4 * g + 3] = b1.w;
        }
        __builtin_amdgcn_s_setprio(1);
#pragma unroll
        for (int c = 0; c < 4; c++) {
            const int pc = ((2 * c + hib) ^ sw) * 8;
            f16x8 a0 = *(const f16x8*)&sK[cur][rp0 + pc];
            f16x8 a1 = *(const f16x8*)&sK[cur][rp1 + pc];
            S0 = __builtin_amdgcn_mfma_f32_32x32x16_f16(a0, qh[c], S0, 0, 0, 0);
            S1 = __builtin_amdgcn_mfma_f32_32x32x16_f16(a1, qh[c], S1, 0, 0, 0);
        }
        __builtin_amdgcn_s_setprio(0);

        // p = exp2(S + bias); pack to bf16 (fp32 range -> no overflow, no max needed)
        unsigned pq[8][2];
#pragma unroll
        for (int g = 0; g < 8; g++) {
            float p0, p1, p2, p3;
            if (g < 4) {
                p0 = __builtin_amdgcn_exp2f(S0[4*g+0]);
                p1 = __builtin_amdgcn_exp2f(S0[4*g+1]);
                p2 = __builtin_amdgcn_exp2f(S0[4*g+2]);
                p3 = __builtin_amdgcn_exp2f(S0[4*g+3]);
            } else {
                p0 = __builtin_amdgcn_exp2f(S1[4*(g-4)+0]);
                p1 = __builtin_amdgcn_exp2f(S1[4*(g-4)+1]);
                p2 = __builtin_amdgcn_exp2f(S1[4*(g-4)+2]);
                p3 = __builtin_amdgcn_exp2f(S1[4*(g-4)+3]);
            }
            lrun += (p0 + p1) + (p2 + p3);
            pq[g][0] = pack_bf16_trunc(p0, p1);
            pq[g][1] = pack_bf16_trunc(p2, p3);
        }

        // O^T += V^T · P^T  (bf16; P fragment for chunk c = lane-local quads 2c,2c+1)
        __builtin_amdgcn_s_setprio(1);
#pragma unroll
        for (int c = 0; c < 4; c++) {
            union { unsigned u[4]; bf16x8 v; } pf;
            pf.u[0] = pq[2 * c][0];     pf.u[1] = pq[2 * c][1];
            pf.u[2] = pq[2 * c + 1][0]; pf.u[3] = pq[2 * c + 1][1];
            const int pc = ((2 * c + hib) ^ sw) * 8;
            bf16x8 v0 = *(const bf16x8*)&sV[cur][rp0 + pc];
            bf16x8 v1 = *(const bf16x8*)&sV[cur][rp1 + pc];
            O0 = __builtin_amdgcn_mfma_f32_32x32x16_bf16(v0, pf.v, O0, 0, 0, 0);
            O1 = __builtin_amdgcn_mfma_f32_32x32x16_bf16(v1, pf.v, O1, 0, 0, 0);
        }
        __builtin_amdgcn_s_setprio(0);
        __syncthreads();
        cur ^= 1;
    }

    lrun += __shfl_xor(lrun, 32);     // other key-half lives in lane^32
    const float linv = 1.f / lrun;
    float* obase = Op + ((size_t)(b * NLQ + q)) * (NH * 64) + h * 64;
#pragma unroll
    for (int me = 0; me < 2; me++) {
#pragma unroll
        for (int g = 0; g < 4; g++) {
            int e0 = me * 32 + 8 * g + 4 * hib;
            float4 o;
            if (me == 0) {
                o.x = O0[4 * g + 0] * linv; o.y = O0[4 * g + 1] * linv;
                o.z = O0[4 * g + 2] * linv; o.w = O0[4 * g + 3] * linv;
            } else {
                o.x = O1[4 * g + 0] * linv; o.y = O1[4 * g + 1] * linv;
                o.z = O1[4 * g + 2] * linv; o.w = O1[4 * g + 3] * linv;
            }
            *(float4*)&obase[e0] = o;
        }
    }
}

// ---------------- LayerNorm (unchanged).
__global__ __launch_bounds__(256) void ln_kernel(const float* __restrict__ X,
                                                 const float* __restrict__ gamma,
                                                 const float* __restrict__ beta,
                                                 float* __restrict__ out) {
    const int row = blockIdx.x * 4 + (threadIdx.x >> 6);
    const int lane = threadIdx.x & 63;
    const float* x = &X[(size_t)row * 512];
    float4 v0 = *(const float4*)&x[lane * 8];
    float4 v1 = *(const float4*)&x[lane * 8 + 4];
    float sum = v0.x + v0.y + v0.z + v0.w + v1.x + v1.y + v1.z + v1.w;
    float sq = v0.x * v0.x + v0.y * v0.y + v0.z * v0.z + v0.w * v0.w
             + v1.x * v1.x + v1.y * v1.y + v1.z * v1.z + v1.w * v1.w;
#pragma unroll
    for (int off = 32; off > 0; off >>= 1) {
        sum += __shfl_down(sum, off);
        sq  += __shfl_down(sq, off);
    }
    sum = __shfl(sum, 0);
    sq  = __shfl(sq, 0);
    const float mean = sum * (1.f / 512.f);
    const float var = sq * (1.f / 512.f) - mean * mean;
    const float rstd = rsqrtf(var + 1e-14f);
    const float g = gamma[0], be = beta[0];
    float* o = &out[(size_t)row * 512];
    float4 r0, r1;
    r0.x = (v0.x - mean) * rstd * g + be;  r0.y = (v0.y - mean) * rstd * g + be;
    r0.z = (v0.z - mean) * rstd * g + be;  r0.w = (v0.w - mean) * rstd * g + be;
    r1.x = (v1.x - mean) * rstd * g + be;  r1.y = (v1.y - mean) * rstd * g + be;
    r1.z = (v1.z - mean) * rstd * g + be;  r1.w = (v1.w - mean) * rstd * g + be;
    *(float4*)&o[lane * 8] = r0;
    *(float4*)&o[lane * 8 + 4] = r1;
}

extern "C" void kernel_launch(void* const* d_in, const int* in_sizes, int n_in,
                              void* d_out, int out_size, void* d_ws, size_t ws_size,
                              hipStream_t stream) {
    const float* query = (const float*)d_in[0];
    const float* key_t = (const float*)d_in[1];
    const float* value = (const float*)d_in[2];
    const float* mask  = (const float*)d_in[3];
    const float* Wq    = (const float*)d_in[4];
    const float* Wk    = (const float*)d_in[5];
    const float* Wv    = (const float*)d_in[6];
    const float* gamma = (const float*)d_in[7];
    const float* beta  = (const float*)d_in[8];
    float* out = (float*)d_out;

    const size_t A = (size_t)NB * NLQ * ND;        // 4,194,304 (= per-tensor size)
    const size_t WS = (size_t)NH * 64 * ND;        // 262,144
    ushort_t* Qf = (ushort_t*)d_ws;                // fp16 (b,h,l,64), *log2e
    ushort_t* Kf = Qf + A;                          // fp16 (b,h,l,64)
    ushort_t* Vt = Qf + 2 * A;                      // bf16 (b,h,e,l)
    ushort_t* Wt = Qf + 3 * A;                      // fp16 Wt, 3 tensors contiguous

    wsplit_kernel<<<dim3(ND / 64, NH, 3), 256, 0, stream>>>(
        Wq, Wk, Wv, Wt, Wt + WS, Wt + 2 * WS);

    proj_gemm_kernel<<<768, 256, 0, stream>>>(
        query, key_t, value, Wt, Qf);

    attn_kernel<<<256, 512, 0, stream>>>(Qf, Kf, Vt, mask, out);

    ln_kernel<<<(NB * NLQ) / 4, 256, 0, stream>>>(out, gamma, beta, out);
}

// Round 12
// 155.170 us; speedup vs baseline: 1.7573x; 1.0170x over previous
//
#include <hip/hip_runtime.h>
#include <math.h>

#define NB 8
#define NLQ 1024
#define NLK 1024
#define ND 512
#define NH 8
#define MASKV -1e30f
#define LOG2E 1.44269504088896f
#define SHIFT2 32.0f   // fixed exp2-domain shift (replaces running max)

typedef unsigned short ushort_t;
typedef __attribute__((ext_vector_type(8))) _Float16 f16x8;
typedef __attribute__((ext_vector_type(8))) short bf16x8;
typedef __attribute__((ext_vector_type(16))) float f32x16;

__device__ __forceinline__ ushort_t f2h_bits(float f) {
    union { _Float16 h; ushort_t u; } v; v.h = (_Float16)f;
    return v.u;
}
__device__ __forceinline__ ushort_t f2bf(float f) {
    union { float f; unsigned u; } v; v.f = f;
    unsigned r = v.u + 0x7fffu + ((v.u >> 16) & 1u);
    return (ushort_t)(r >> 16);
}
__device__ __forceinline__ void gload16(const ushort_t* g, ushort_t* l) {
    __builtin_amdgcn_global_load_lds(
        (const __attribute__((address_space(1))) void*)g,
        (__attribute__((address_space(3))) void*)l, 16, 0, 0);
}
// pack bf16(p0) | bf16(p1)<<16, truncating (p >= 0)
__device__ __forceinline__ unsigned pack_bf16_trunc(float p0, float p1) {
    return __builtin_amdgcn_perm(__float_as_uint(p1), __float_as_uint(p0),
                                 0x07060302u);
}

// ---------------- W transpose: W (H,512,64) fp32 -> Wt (H,64,512) fp16
__global__ __launch_bounds__(256) void wsplit_kernel(
    const float* __restrict__ Wq, const float* __restrict__ Wk, const float* __restrict__ Wv,
    ushort_t* __restrict__ oq, ushort_t* __restrict__ ok, ushort_t* __restrict__ ov) {
    __shared__ float T[64][65];
    const int d0 = blockIdx.x * 64;
    const int h  = blockIdx.y;
    const int t  = blockIdx.z;
    const float* W = (t == 0) ? Wq : (t == 1) ? Wk : Wv;
    ushort_t* oh = (t == 0) ? oq : (t == 1) ? ok : ov;
    const int tid = threadIdx.x;
#pragma unroll
    for (int i = 0; i < 4; i++) {
        int r = (tid >> 4) + i * 16;
        int c = (tid & 15) * 4;
        float4 v = *(const float4*)&W[((size_t)h * ND + d0 + r) * 64 + c];
        *(float4*)&T[r][c] = v;
    }
    __syncthreads();
    const int e = tid & 63;
    const int dg = tid >> 6;
    ushort_t hs[16];
#pragma unroll
    for (int dd = 0; dd < 16; dd++) hs[dd] = f2h_bits(T[dg * 16 + dd][e]);
    size_t base = ((size_t)h * 64 + e) * ND + d0 + dg * 16;
#pragma unroll
    for (int c = 0; c < 2; c++) {
        uint4 wh;
        wh.x = (unsigned)hs[8*c+0] | ((unsigned)hs[8*c+1] << 16);
        wh.y = (unsigned)hs[8*c+2] | ((unsigned)hs[8*c+3] << 16);
        wh.z = (unsigned)hs[8*c+4] | ((unsigned)hs[8*c+5] << 16);
        wh.w = (unsigned)hs[8*c+6] | ((unsigned)hs[8*c+7] << 16);
        *(uint4*)&oh[base + 8 * c] = wh;
    }
}

// ---------------- Projection GEMM (R9 structure, unchanged — best measured).
// M=24576 (t,b,l), N=512 (h,e), K=512. 128x128 tile, BK=64, 4 waves x 2x2.
// A single-buffered (reg pre-read + no-vmcnt-drain barrier), B dbuf DMA.
// Grid 768 = 256 CUs x 3 blocks, 49.9 KB LDS.
__global__ __launch_bounds__(256, 3) void proj_gemm_kernel(
    const float* __restrict__ Xq, const float* __restrict__ Xk,
    const float* __restrict__ Xv, const ushort_t* __restrict__ Wbase,
    ushort_t* __restrict__ Obase) {
    __shared__ ushort_t S[24960];      // sA(8320) + sB0(8320) + sB1(8320)
    ushort_t* const sA  = S;
    ushort_t* const sB0 = S + 8320;
    ushort_t* const sB1 = S + 16640;

    const int bid   = blockIdx.x;
    const int y     = bid / 192;        // N-tile (2 heads)
    const int mglob = bid % 192;
    const int t  = mglob >> 6;          // tensor 0..2
    const int b  = (mglob >> 3) & 7;
    const int l0 = (mglob & 7) * 128;

    const int tid  = threadIdx.x;
    const int wave = tid >> 6;
    const int lane = tid & 63;
    const int l31  = lane & 31;
    const int hib  = lane >> 5;
    const int wr = wave >> 1, wc = wave & 1;

    const float* Xt = (t == 0) ? Xq : (t == 1) ? Xk : Xv;
    const float* gx = Xt + ((size_t)b * NLQ + l0) * ND;
    const ushort_t* gwt = Wbase + (size_t)t * ((size_t)NH * 64 * ND)
                        + (size_t)y * 128 * ND;
    ushort_t* out = Obase + (size_t)t * ((size_t)NB * NH * NLQ * 64);

    const int srow = lane >> 3;             // row in 8-row group
    const int schk = (lane & 7) ^ srow;     // source chunk swizzle

    float4 ax[4][2];
    auto aload = [&](int d0) {
#pragma unroll
        for (int j = 0; j < 4; j++) {
            int row = (j * 4 + wave) * 8 + srow;
            const float* p = gx + (size_t)row * ND + d0 + schk * 8;
            ax[j][0] = *(const float4*)p;
            ax[j][1] = *(const float4*)(p + 4);
        }
    };
    auto awrite = [&]() {
#pragma unroll
        for (int j = 0; j < 4; j++) {
            int u = j * 4 + wave;
            uint4 hv;
            hv.x = (unsigned)f2h_bits(ax[j][0].x) | ((unsigned)f2h_bits(ax[j][0].y) << 16);
            hv.y = (unsigned)f2h_bits(ax[j][0].z) | ((unsigned)f2h_bits(ax[j][0].w) << 16);
            hv.z = (unsigned)f2h_bits(ax[j][1].x) | ((unsigned)f2h_bits(ax[j][1].y) << 16);
            hv.w = (unsigned)f2h_bits(ax[j][1].z) | ((unsigned)f2h_bits(ax[j][1].w) << 16);
            *(uint4*)(sA + u * 520 + lane * 8) = hv;
        }
    };
    auto bstage = [&](ushort_t* dst, int d0) {
#pragma unroll
        for (int j = 0; j < 4; j++) {
            int u = j * 4 + wave;
            int row = u * 8 + srow;
            gload16(gwt + (size_t)row * ND + d0 + schk * 8, dst + u * 520);
        }
    };

    f32x16 acc00, acc01, acc10, acc11;
#pragma unroll
    for (int i = 0; i < 16; i++) { acc00[i] = 0.f; acc01[i] = 0.f;
                                   acc10[i] = 0.f; acc11[i] = 0.f; }

    const int ga  = wr * 8 + (l31 >> 3);    // A group, mi=0 (mi=1: +4)
    const int gb  = wc * 8 + (l31 >> 3);    // B group, ni=0 (ni=1: +4)
    const int ro  = (l31 & 7) * 64;         // row-in-group offset (ushorts)
    const int swz = l31 & 7;                // read-side chunk swizzle

    // prologue: chunk 0 into sA + sB0
    aload(0);
    awrite();                                // compiler waits vmcnt for ax
    bstage(sB0, 0);
    asm volatile("s_waitcnt vmcnt(0) lgkmcnt(0)" ::: "memory");
    __builtin_amdgcn_sched_barrier(0);
    __builtin_amdgcn_s_barrier();
    __builtin_amdgcn_sched_barrier(0);

    ushort_t* sBc = sB0;
    ushort_t* sBn = sB1;
#pragma unroll
    for (int kc = 0; kc < 8; kc++) {
        if (kc < 7) aload((kc + 1) * 64);   // A global loads span both phases
        f16x8 a0[4], a1[4];
#pragma unroll
        for (int c = 0; c < 4; c++) {
            const int pc = ((2 * c + hib) ^ swz) * 8;
            a0[c] = *(const f16x8*)&sA[ga * 520 + ro + pc];
            a1[c] = *(const f16x8*)&sA[(ga + 4) * 520 + ro + pc];
        }
        asm volatile("s_waitcnt lgkmcnt(0)" ::: "memory");  // reads landed
        __builtin_amdgcn_sched_barrier(0);
        __builtin_amdgcn_s_barrier();                       // barrier1 (no vmcnt drain)
        __builtin_amdgcn_sched_barrier(0);
        if (kc < 7) {
            bstage(sBn, (kc + 1) * 64);
            awrite();
        }
#pragma unroll
        for (int c = 0; c < 4; c++) {
            const int pc = ((2 * c + hib) ^ swz) * 8;
            f16x8 b0 = *(const f16x8*)&sBc[gb * 520 + ro + pc];
            f16x8 b1 = *(const f16x8*)&sBc[(gb + 4) * 520 + ro + pc];
            acc00 = __builtin_amdgcn_mfma_f32_32x32x16_f16(a0[c], b0, acc00, 0, 0, 0);
            acc01 = __builtin_amdgcn_mfma_f32_32x32x16_f16(a0[c], b1, acc01, 0, 0, 0);
            acc10 = __builtin_amdgcn_mfma_f32_32x32x16_f16(a1[c], b0, acc10, 0, 0, 0);
            acc11 = __builtin_amdgcn_mfma_f32_32x32x16_f16(a1[c], b1, acc11, 0, 0, 0);
        }
        if (kc < 7) {
            asm volatile("s_waitcnt vmcnt(0) lgkmcnt(0)" ::: "memory");
            __builtin_amdgcn_sched_barrier(0);
            __builtin_amdgcn_s_barrier();                   // barrier2
            __builtin_amdgcn_sched_barrier(0);
        }
        ushort_t* tmp = sBc; sBc = sBn; sBn = tmp;
    }

    if (t < 2) {
        const float scale = (t == 0) ? LOG2E : 1.f;
#pragma unroll
        for (int mi = 0; mi < 2; mi++) {
#pragma unroll
            for (int ni = 0; ni < 2; ni++) {
                const f32x16& a = (mi == 0) ? (ni == 0 ? acc00 : acc01)
                                            : (ni == 0 ? acc10 : acc11);
                int nglob = y * 128 + wc * 64 + ni * 32 + l31;
                int hh = nglob >> 6, e = nglob & 63;
                size_t obase = (((size_t)b * NH + hh) * NLQ + l0) * 64 + e;
#pragma unroll
                for (int r = 0; r < 16; r++) {
                    int l = wr * 64 + mi * 32 + (r & 3) + 8 * (r >> 2) + 4 * hib;
                    out[obase + (size_t)l * 64] = f2h_bits(a[r] * scale);
                }
            }
        }
    } else {
        __syncthreads();
        ushort_t (*T)[130] = (ushort_t(*)[130])S;
#pragma unroll
        for (int mi = 0; mi < 2; mi++) {
#pragma unroll
            for (int ni = 0; ni < 2; ni++) {
                const f32x16& a = (mi == 0) ? (ni == 0 ? acc00 : acc01)
                                            : (ni == 0 ? acc10 : acc11);
                int n_loc = wc * 64 + ni * 32 + l31;
#pragma unroll
                for (int r = 0; r < 16; r++) {
                    int l = wr * 64 + mi * 32 + (r & 3) + 8 * (r >> 2) + 4 * hib;
                    T[n_loc][l] = f2bf(a[r]);
                }
            }
        }
        __syncthreads();
        const int n_loc = tid >> 1;
        const int half  = tid & 1;
        const int hh = n_loc >> 6, e = n_loc & 63;
        size_t obase = (((size_t)b * NH + y * 2 + hh) * 64 + e) * NLK
                     + l0 + half * 64;
        const ushort_t* src = &T[n_loc][half * 64];
#pragma unroll
        for (int c2 = 0; c2 < 8; c2++)
            *(uint4*)&out[obase + c2 * 8] = *(const uint4*)&src[c2 * 8];
    }
}

// ---------------- MFMA flash attention (R12: 16 waves, K-split).
// 1024 threads = 8 q-strips x 2 k-groups; group g owns K-tiles g*8..g*8+7
// with its own K/V double-buffer. Fixed-shift softmax (no running max) makes
// the cross-group combine a pure sum: O += O_partner, lrun += lrun_partner
// (LDS, one-shot, conflict-free). Grid 256 (idx&63 = bh), 16 waves/CU.
__global__ __launch_bounds__(1024, 1) void attn_kernel(
    const ushort_t* __restrict__ Qf, const ushort_t* __restrict__ Kf,
    const ushort_t* __restrict__ Vt, const float* __restrict__ maskp,
    float* __restrict__ Op) {
    __shared__ ushort_t SMEM[33280];   // 8 buffers x 4160 ushorts = 66560 B
    __shared__ float sBias[1024];

    const int idx = blockIdx.x;
    const int bh_i = idx & 63;
    const int qc  = idx >> 6;          // 0..3
    const int b = bh_i >> 3, h = bh_i & 7;
    const size_t bh = (size_t)b * NH + h;

    const int tid   = threadIdx.x;
    const int wave  = tid >> 6;        // 0..15
    const int strip = wave >> 1;       // q-strip 0..7
    const int grp   = wave & 1;        // k-group 0..1
    const int lane  = tid & 63;
    const int l31   = lane & 31;
    const int hib   = lane >> 5;
    const int q = qc * 256 + strip * 32 + l31;
    const int sw = l31 & 7;

    // buffer layout: [grp][buf][K|V]
    auto sKp = [&](int g, int bf) { return SMEM + (g * 4 + bf * 2 + 0) * 4160; };
    auto sVp = [&](int g, int bf) { return SMEM + (g * 4 + bf * 2 + 1) * 4160; };

    // bias = mask ? -SHIFT2 : -1e30  (exp2-domain shift + mask in one constant)
    if (tid < 256) {
        const float* mrow = maskp + ((size_t)b << 10);
        float4 m0 = *(const float4*)&mrow[tid * 4];
        float4 bi;
        bi.x = (m0.x > 0.5f) ? -SHIFT2 : MASKV;
        bi.y = (m0.y > 0.5f) ? -SHIFT2 : MASKV;
        bi.z = (m0.z > 0.5f) ? -SHIFT2 : MASKV;
        bi.w = (m0.w > 0.5f) ? -SHIFT2 : MASKV;
        *(float4*)&sBias[tid * 4] = bi;
    }

    f16x8 qh[4];
    {
        const ushort_t* ph = Qf + (bh * NLQ + q) * 64 + hib * 8;
#pragma unroll
        for (int c = 0; c < 4; c++) qh[c] = *(const f16x8*)(ph + c * 16);
    }

    const int srow = lane >> 3;
    const int schk = (lane & 7) ^ srow;

    // K rows permuted (storage row s holds key swap23(s)); V natural; group-padded
    // 16 staging units per k-group spread over its 8 waves (2 each).
    auto stage = [&](int buf, int k0) {
#pragma unroll
        for (int n = 0; n < 2; n++) {
            int u = strip + n * 8;          // 0..15, uniform per wave
            if (u < 8) {
                int row = u * 8 + srow;
                int key = (row & ~12) | ((row & 4) << 1) | ((row & 8) >> 1);
                gload16(Kf + ((bh << 10) + k0 + key) * 64 + schk * 8,
                        sKp(grp, buf) + u * 520);
            } else {
                int u8 = u - 8;
                int row = u8 * 8 + srow;
                gload16(Vt + ((bh << 6) + row) * NLK + k0 + schk * 8,
                        sVp(grp, buf) + u8 * 520);
            }
        }
    };

    f32x16 O0, O1;
#pragma unroll
    for (int i = 0; i < 16; i++) { O0[i] = 0.f; O1[i] = 0.f; }
    float lrun = 0.f;

    const int rp0 = (l31 >> 3) * 520 + (l31 & 7) * 64;   // rows 0..31
    const int rp1 = rp0 + 4 * 520;                        // rows 32..63

    stage(0, grp * 512);
    __syncthreads();
    int cur = 0;

    for (int t = 0; t < 8; t++) {
        const int k0 = (grp * 8 + t) << 6;
        if (t < 7) stage(cur ^ 1, k0 + 64);

        // S init = bias (C-operand); quad g of half s holds keys
        // k0 + 32s + 16(g>>1) + 8hib + 4(g&1) + {0..3}
        f32x16 S0, S1;
#pragma unroll
        for (int g = 0; g < 4; g++) {
            const int kb = k0 + 16 * (g >> 1) + 8 * hib + 4 * (g & 1);
            float4 b0 = *(const float4*)&sBias[kb];
            float4 b1 = *(const float4*)&sBias[kb + 32];
            S0[4 * g + 0] = b0.x; S0[4 * g + 1] = b0.y;
            S0[4 * g + 2] = b0.z; S0[4 * g + 3] = b0.w;
            S1[4 * g + 0] = b1.x; S1[4 * g + 1] = b1.y;
            S1[4 * g + 2] = b1.z; S1[4 * g + 3] = b1.w;
        }
        __builtin_amdgcn_s_setprio(1);
#pragma unroll
        for (int c = 0; c < 4; c++) {
            const int pc = ((2 * c + hib) ^ sw) * 8;
            f16x8 a0 = *(const f16x8*)&sKp(grp, cur)[rp0 + pc];
            f16x8 a1 = *(const f16x8*)&sKp(grp, cur)[rp1 + pc];
            S0 = __builtin_amdgcn_mfma_f32_32x32x16_f16(a0, qh[c], S0, 0, 0, 0);
            S1 = __builtin_amdgcn_mfma_f32_32x32x16_f16(a1, qh[c], S1, 0, 0, 0);
        }
        __builtin_amdgcn_s_setprio(0);

        // p = exp2(S + bias); pack to bf16 (fp32 range -> no overflow, no max needed)
        unsigned pq[8][2];
#pragma unroll
        for (int g = 0; g < 8; g++) {
            float p0, p1, p2, p3;
            if (g < 4) {
                p0 = __builtin_amdgcn_exp2f(S0[4*g+0]);
                p1 = __builtin_amdgcn_exp2f(S0[4*g+1]);
                p2 = __builtin_amdgcn_exp2f(S0[4*g+2]);
                p3 = __builtin_amdgcn_exp2f(S0[4*g+3]);
            } else {
                p0 = __builtin_amdgcn_exp2f(S1[4*(g-4)+0]);
                p1 = __builtin_amdgcn_exp2f(S1[4*(g-4)+1]);
                p2 = __builtin_amdgcn_exp2f(S1[4*(g-4)+2]);
                p3 = __builtin_amdgcn_exp2f(S1[4*(g-4)+3]);
            }
            lrun += (p0 + p1) + (p2 + p3);
            pq[g][0] = pack_bf16_trunc(p0, p1);
            pq[g][1] = pack_bf16_trunc(p2, p3);
        }

        // O^T += V^T · P^T  (bf16; P fragment for chunk c = lane-local quads 2c,2c+1)
        __builtin_amdgcn_s_setprio(1);
#pragma unroll
        for (int c = 0; c < 4; c++) {
            union { unsigned u[4]; bf16x8 v; } pf;
            pf.u[0] = pq[2 * c][0];     pf.u[1] = pq[2 * c][1];
            pf.u[2] = pq[2 * c + 1][0]; pf.u[3] = pq[2 * c + 1][1];
            const int pc = ((2 * c + hib) ^ sw) * 8;
            bf16x8 v0 = *(const bf16x8*)&sVp(grp, cur)[rp0 + pc];
            bf16x8 v1 = *(const bf16x8*)&sVp(grp, cur)[rp1 + pc];
            O0 = __builtin_amdgcn_mfma_f32_32x32x16_bf16(v0, pf.v, O0, 0, 0, 0);
            O1 = __builtin_amdgcn_mfma_f32_32x32x16_bf16(v1, pf.v, O1, 0, 0, 0);
        }
        __builtin_amdgcn_s_setprio(0);
        __syncthreads();
        cur ^= 1;
    }

    // ---- cross-group combine (fixed-shift softmax: pure sums, no rescale)
    float* scr = (float*)SMEM;               // 66560 B >= 8 strips x 8 KB
    float* slr = (float*)sBias;              // lrun scratch (bias dead now)
    if (grp == 1) {
        float* basep = scr + strip * 2048;
#pragma unroll
        for (int i = 0; i < 16; i++) {
            basep[i * 64 + lane]        = O0[i];
            basep[(16 + i) * 64 + lane] = O1[i];
        }
        slr[strip * 64 + lane] = lrun;
    }
    __syncthreads();
    if (grp == 0) {
        float* basep = scr + strip * 2048;
#pragma unroll
        for (int i = 0; i < 16; i++) {
            O0[i] += basep[i * 64 + lane];
            O1[i] += basep[(16 + i) * 64 + lane];
        }
        lrun += slr[strip * 64 + lane];

        lrun += __shfl_xor(lrun, 32);     // other key-half lives in lane^32
        const float linv = 1.f / lrun;
        float* obase = Op + ((size_t)(b * NLQ + q)) * (NH * 64) + h * 64;
#pragma unroll
        for (int me = 0; me < 2; me++) {
#pragma unroll
            for (int g = 0; g < 4; g++) {
                int e0 = me * 32 + 8 * g + 4 * hib;
                float4 o;
                if (me == 0) {
                    o.x = O0[4 * g + 0] * linv; o.y = O0[4 * g + 1] * linv;
                    o.z = O0[4 * g + 2] * linv; o.w = O0[4 * g + 3] * linv;
                } else {
                    o.x = O1[4 * g + 0] * linv; o.y = O1[4 * g + 1] * linv;
                    o.z = O1[4 * g + 2] * linv; o.w = O1[4 * g + 3] * linv;
                }
                *(float4*)&obase[e0] = o;
            }
        }
    }
}

// ---------------- LayerNorm (unchanged).
__global__ __launch_bounds__(256) void ln_kernel(const float* __restrict__ X,
                                                 const float* __restrict__ gamma,
                                                 const float* __restrict__ beta,
                                                 float* __restrict__ out) {
    const int row = blockIdx.x * 4 + (threadIdx.x >> 6);
    const int lane = threadIdx.x & 63;
    const float* x = &X[(size_t)row * 512];
    float4 v0 = *(const float4*)&x[lane * 8];
    float4 v1 = *(const float4*)&x[lane * 8 + 4];
    float sum = v0.x + v0.y + v0.z + v0.w + v1.x + v1.y + v1.z + v1.w;
    float sq = v0.x * v0.x + v0.y * v0.y + v0.z * v0.z + v0.w * v0.w
             + v1.x * v1.x + v1.y * v1.y + v1.z * v1.z + v1.w * v1.w;
#pragma unroll
    for (int off = 32; off > 0; off >>= 1) {
        sum += __shfl_down(sum, off);
        sq  += __shfl_down(sq, off);
    }
    sum = __shfl(sum, 0);
    sq  = __shfl(sq, 0);
    const float mean = sum * (1.f / 512.f);
    const float var = sq * (1.f / 512.f) - mean * mean;
    const float rstd = rsqrtf(var + 1e-14f);
    const float g = gamma[0], be = beta[0];
    float* o = &out[(size_t)row * 512];
    float4 r0, r1;
    r0.x = (v0.x - mean) * rstd * g + be;  r0.y = (v0.y - mean) * rstd * g + be;
    r0.z = (v0.z - mean) * rstd * g + be;  r0.w = (v0.w - mean) * rstd * g + be;
    r1.x = (v1.x - mean) * rstd * g + be;  r1.y = (v1.y - mean) * rstd * g + be;
    r1.z = (v1.z - mean) * rstd * g + be;  r1.w = (v1.w - mean) * rstd * g + be;
    *(float4*)&o[lane * 8] = r0;
    *(float4*)&o[lane * 8 + 4] = r1;
}

extern "C" void kernel_launch(void* const* d_in, const int* in_sizes, int n_in,
                              void* d_out, int out_size, void* d_ws, size_t ws_size,
                              hipStream_t stream) {
    const float* query = (const float*)d_in[0];
    const float* key_t = (const float*)d_in[1];
    const float* value = (const float*)d_in[2];
    const float* mask  = (const float*)d_in[3];
    const float* Wq    = (const float*)d_in[4];
    const float* Wk    = (const float*)d_in[5];
    const float* Wv    = (const float*)d_in[6];
    const float* gamma = (const float*)d_in[7];
    const float* beta  = (const float*)d_in[8];
    float* out = (float*)d_out;

    const size_t A = (size_t)NB * NLQ * ND;        // 4,194,304 (= per-tensor size)
    const size_t WS = (size_t)NH * 64 * ND;        // 262,144
    ushort_t* Qf = (ushort_t*)d_ws;                // fp16 (b,h,l,64), *log2e
    ushort_t* Kf = Qf + A;                          // fp16 (b,h,l,64)
    ushort_t* Vt = Qf + 2 * A;                      // bf16 (b,h,e,l)
    ushort_t* Wt = Qf + 3 * A;                      // fp16 Wt, 3 tensors contiguous

    wsplit_kernel<<<dim3(ND / 64, NH, 3), 256, 0, stream>>>(
        Wq, Wk, Wv, Wt, Wt + WS, Wt + 2 * WS);

    proj_gemm_kernel<<<768, 256, 0, stream>>>(
        query, key_t, value, Wt, Qf);

    attn_kernel<<<256, 1024, 0, stream>>>(Qf, Kf, Vt, mask, out);

    ln_kernel<<<(NB * NLQ) / 4, 256, 0, stream>>>(out, gamma, beta, out);
}

// Round 13
// 154.319 us; speedup vs baseline: 1.7669x; 1.0055x over previous
//
#include <hip/hip_runtime.h>
#include <math.h>

#define NB 8
#define NLQ 1024
#define NLK 1024
#define ND 512
#define NH 8
#define MASKV -1e30f
#define LOG2E 1.44269504088896f
#define SHIFT2 32.0f   // fixed exp2-domain shift (replaces running max)

typedef unsigned short ushort_t;
typedef __attribute__((ext_vector_type(8))) _Float16 f16x8;
typedef __attribute__((ext_vector_type(8))) short bf16x8;
typedef __attribute__((ext_vector_type(16))) float f32x16;

__device__ __forceinline__ ushort_t f2h_bits(float f) {
    union { _Float16 h; ushort_t u; } v; v.h = (_Float16)f;
    return v.u;
}
__device__ __forceinline__ ushort_t f2bf(float f) {
    union { float f; unsigned u; } v; v.f = f;
    unsigned r = v.u + 0x7fffu + ((v.u >> 16) & 1u);
    return (ushort_t)(r >> 16);
}
__device__ __forceinline__ void gload16(const ushort_t* g, ushort_t* l) {
    __builtin_amdgcn_global_load_lds(
        (const __attribute__((address_space(1))) void*)g,
        (__attribute__((address_space(3))) void*)l, 16, 0, 0);
}
// pack bf16(p0) | bf16(p1)<<16, truncating (p >= 0)
__device__ __forceinline__ unsigned pack_bf16_trunc(float p0, float p1) {
    return __builtin_amdgcn_perm(__float_as_uint(p1), __float_as_uint(p0),
                                 0x07060302u);
}

// ---------------- W transpose: W (H,512,64) fp32 -> Wt (H,64,512) fp16
__global__ __launch_bounds__(256) void wsplit_kernel(
    const float* __restrict__ Wq, const float* __restrict__ Wk, const float* __restrict__ Wv,
    ushort_t* __restrict__ oq, ushort_t* __restrict__ ok, ushort_t* __restrict__ ov) {
    __shared__ float T[64][65];
    const int d0 = blockIdx.x * 64;
    const int h  = blockIdx.y;
    const int t  = blockIdx.z;
    const float* W = (t == 0) ? Wq : (t == 1) ? Wk : Wv;
    ushort_t* oh = (t == 0) ? oq : (t == 1) ? ok : ov;
    const int tid = threadIdx.x;
#pragma unroll
    for (int i = 0; i < 4; i++) {
        int r = (tid >> 4) + i * 16;
        int c = (tid & 15) * 4;
        float4 v = *(const float4*)&W[((size_t)h * ND + d0 + r) * 64 + c];
        *(float4*)&T[r][c] = v;
    }
    __syncthreads();
    const int e = tid & 63;
    const int dg = tid >> 6;
    ushort_t hs[16];
#pragma unroll
    for (int dd = 0; dd < 16; dd++) hs[dd] = f2h_bits(T[dg * 16 + dd][e]);
    size_t base = ((size_t)h * 64 + e) * ND + d0 + dg * 16;
#pragma unroll
    for (int c = 0; c < 2; c++) {
        uint4 wh;
        wh.x = (unsigned)hs[8*c+0] | ((unsigned)hs[8*c+1] << 16);
        wh.y = (unsigned)hs[8*c+2] | ((unsigned)hs[8*c+3] << 16);
        wh.z = (unsigned)hs[8*c+4] | ((unsigned)hs[8*c+5] << 16);
        wh.w = (unsigned)hs[8*c+6] | ((unsigned)hs[8*c+7] << 16);
        *(uint4*)&oh[base + 8 * c] = wh;
    }
}

// ---------------- Projection GEMM (R13: stall-free reorder of R9 schedule).
// M=24576 (t,b,l), N=512 (h,e), K=512. 128x128 tile, BK=64, 4 waves x 2x2.
// A single-buffered, B dbuf DMA, 49.9 KB LDS, grid 768 = 256 CUs x 3 blocks.
// R13 change (zero-cost): awrite moved AFTER the MFMA phase (barrier1 already
// guarantees all sA reads done) -> awrite's vmcnt cover grows ~150->~600 cyc;
// bstage issued BEFORE the MFMA -> its vmcnt(0) drain cover grows ~130->~500.
__global__ __launch_bounds__(256, 3) void proj_gemm_kernel(
    const float* __restrict__ Xq, const float* __restrict__ Xk,
    const float* __restrict__ Xv, const ushort_t* __restrict__ Wbase,
    ushort_t* __restrict__ Obase) {
    __shared__ ushort_t S[24960];      // sA(8320) + sB0(8320) + sB1(8320)
    ushort_t* const sA  = S;
    ushort_t* const sB0 = S + 8320;
    ushort_t* const sB1 = S + 16640;

    const int bid   = blockIdx.x;
    const int y     = bid / 192;        // N-tile (2 heads)
    const int mglob = bid % 192;
    const int t  = mglob >> 6;          // tensor 0..2
    const int b  = (mglob >> 3) & 7;
    const int l0 = (mglob & 7) * 128;

    const int tid  = threadIdx.x;
    const int wave = tid >> 6;
    const int lane = tid & 63;
    const int l31  = lane & 31;
    const int hib  = lane >> 5;
    const int wr = wave >> 1, wc = wave & 1;

    const float* Xt = (t == 0) ? Xq : (t == 1) ? Xk : Xv;
    const float* gx = Xt + ((size_t)b * NLQ + l0) * ND;
    const ushort_t* gwt = Wbase + (size_t)t * ((size_t)NH * 64 * ND)
                        + (size_t)y * 128 * ND;
    ushort_t* out = Obase + (size_t)t * ((size_t)NB * NH * NLQ * 64);

    const int srow = lane >> 3;             // row in 8-row group
    const int schk = (lane & 7) ^ srow;     // source chunk swizzle

    float4 ax[4][2];
    auto aload = [&](int d0) {
#pragma unroll
        for (int j = 0; j < 4; j++) {
            int row = (j * 4 + wave) * 8 + srow;
            const float* p = gx + (size_t)row * ND + d0 + schk * 8;
            ax[j][0] = *(const float4*)p;
            ax[j][1] = *(const float4*)(p + 4);
        }
    };
    auto awrite = [&]() {
#pragma unroll
        for (int j = 0; j < 4; j++) {
            int u = j * 4 + wave;
            uint4 hv;
            hv.x = (unsigned)f2h_bits(ax[j][0].x) | ((unsigned)f2h_bits(ax[j][0].y) << 16);
            hv.y = (unsigned)f2h_bits(ax[j][0].z) | ((unsigned)f2h_bits(ax[j][0].w) << 16);
            hv.z = (unsigned)f2h_bits(ax[j][1].x) | ((unsigned)f2h_bits(ax[j][1].y) << 16);
            hv.w = (unsigned)f2h_bits(ax[j][1].z) | ((unsigned)f2h_bits(ax[j][1].w) << 16);
            *(uint4*)(sA + u * 520 + lane * 8) = hv;
        }
    };
    auto bstage = [&](ushort_t* dst, int d0) {
#pragma unroll
        for (int j = 0; j < 4; j++) {
            int u = j * 4 + wave;
            int row = u * 8 + srow;
            gload16(gwt + (size_t)row * ND + d0 + schk * 8, dst + u * 520);
        }
    };

    f32x16 acc00, acc01, acc10, acc11;
#pragma unroll
    for (int i = 0; i < 16; i++) { acc00[i] = 0.f; acc01[i] = 0.f;
                                   acc10[i] = 0.f; acc11[i] = 0.f; }

    const int ga  = wr * 8 + (l31 >> 3);    // A group, mi=0 (mi=1: +4)
    const int gb  = wc * 8 + (l31 >> 3);    // B group, ni=0 (ni=1: +4)
    const int ro  = (l31 & 7) * 64;         // row-in-group offset (ushorts)
    const int swz = l31 & 7;                // read-side chunk swizzle

    // prologue: chunk 0 into sA + sB0
    aload(0);
    awrite();                                // compiler waits vmcnt for ax
    bstage(sB0, 0);
    asm volatile("s_waitcnt vmcnt(0) lgkmcnt(0)" ::: "memory");
    __builtin_amdgcn_sched_barrier(0);
    __builtin_amdgcn_s_barrier();
    __builtin_amdgcn_sched_barrier(0);

    ushort_t* sBc = sB0;
    ushort_t* sBn = sB1;
#pragma unroll
    for (int kc = 0; kc < 8; kc++) {
        if (kc < 7) aload((kc + 1) * 64);   // A loads get a full phase of cover
        // pre-read A frags for chunk kc into regs (sA reads complete here)
        f16x8 a0[4], a1[4];
#pragma unroll
        for (int c = 0; c < 4; c++) {
            const int pc = ((2 * c + hib) ^ swz) * 8;
            a0[c] = *(const f16x8*)&sA[ga * 520 + ro + pc];
            a1[c] = *(const f16x8*)&sA[(ga + 4) * 520 + ro + pc];
        }
        asm volatile("s_waitcnt lgkmcnt(0)" ::: "memory");  // reads landed
        __builtin_amdgcn_sched_barrier(0);
        __builtin_amdgcn_s_barrier();                       // barrier1 (no vmcnt drain)
        __builtin_amdgcn_sched_barrier(0);
        // B DMA for kc+1 issues BEFORE the MFMA phase (drain cover = MFMA+awrite)
        if (kc < 7) bstage(sBn, (kc + 1) * 64);
#pragma unroll
        for (int c = 0; c < 4; c++) {
            const int pc = ((2 * c + hib) ^ swz) * 8;
            f16x8 b0 = *(const f16x8*)&sBc[gb * 520 + ro + pc];
            f16x8 b1 = *(const f16x8*)&sBc[(gb + 4) * 520 + ro + pc];
            acc00 = __builtin_amdgcn_mfma_f32_32x32x16_f16(a0[c], b0, acc00, 0, 0, 0);
            acc01 = __builtin_amdgcn_mfma_f32_32x32x16_f16(a0[c], b1, acc01, 0, 0, 0);
            acc10 = __builtin_amdgcn_mfma_f32_32x32x16_f16(a1[c], b0, acc10, 0, 0, 0);
            acc11 = __builtin_amdgcn_mfma_f32_32x32x16_f16(a1[c], b1, acc11, 0, 0, 0);
        }
        if (kc < 7) {
            // awrite AFTER MFMA: barrier1 guaranteed all waves' sA reads done;
            // ax loads now ~600 cyc old -> no vmcnt stall.
            awrite();
            asm volatile("s_waitcnt vmcnt(0) lgkmcnt(0)" ::: "memory");
            __builtin_amdgcn_sched_barrier(0);
            __builtin_amdgcn_s_barrier();                   // barrier2
            __builtin_amdgcn_sched_barrier(0);
        }
        ushort_t* tmp = sBc; sBc = sBn; sBn = tmp;
    }

    if (t < 2) {
        const float scale = (t == 0) ? LOG2E : 1.f;
#pragma unroll
        for (int mi = 0; mi < 2; mi++) {
#pragma unroll
            for (int ni = 0; ni < 2; ni++) {
                const f32x16& a = (mi == 0) ? (ni == 0 ? acc00 : acc01)
                                            : (ni == 0 ? acc10 : acc11);
                int nglob = y * 128 + wc * 64 + ni * 32 + l31;
                int hh = nglob >> 6, e = nglob & 63;
                size_t obase = (((size_t)b * NH + hh) * NLQ + l0) * 64 + e;
#pragma unroll
                for (int r = 0; r < 16; r++) {
                    int l = wr * 64 + mi * 32 + (r & 3) + 8 * (r >> 2) + 4 * hib;
                    out[obase + (size_t)l * 64] = f2h_bits(a[r] * scale);
                }
            }
        }
    } else {
        __syncthreads();
        ushort_t (*T)[130] = (ushort_t(*)[130])S;
#pragma unroll
        for (int mi = 0; mi < 2; mi++) {
#pragma unroll
            for (int ni = 0; ni < 2; ni++) {
                const f32x16& a = (mi == 0) ? (ni == 0 ? acc00 : acc01)
                                            : (ni == 0 ? acc10 : acc11);
                int n_loc = wc * 64 + ni * 32 + l31;
#pragma unroll
                for (int r = 0; r < 16; r++) {
                    int l = wr * 64 + mi * 32 + (r & 3) + 8 * (r >> 2) + 4 * hib;
                    T[n_loc][l] = f2bf(a[r]);
                }
            }
        }
        __syncthreads();
        const int n_loc = tid >> 1;
        const int half  = tid & 1;
        const int hh = n_loc >> 6, e = n_loc & 63;
        size_t obase = (((size_t)b * NH + y * 2 + hh) * 64 + e) * NLK
                     + l0 + half * 64;
        const ushort_t* src = &T[n_loc][half * 64];
#pragma unroll
        for (int c2 = 0; c2 < 8; c2++)
            *(uint4*)&out[obase + c2 * 8] = *(const uint4*)&src[c2 * 8];
    }
}

// ---------------- MFMA flash attention (R12: 16 waves, K-split — unchanged).
// 1024 threads = 8 q-strips x 2 k-groups; group g owns K-tiles g*8..g*8+7
// with its own K/V double-buffer. Fixed-shift softmax makes the cross-group
// combine a pure sum. Grid 256 (idx&63 = bh), 16 waves/CU.
__global__ __launch_bounds__(1024, 1) void attn_kernel(
    const ushort_t* __restrict__ Qf, const ushort_t* __restrict__ Kf,
    const ushort_t* __restrict__ Vt, const float* __restrict__ maskp,
    float* __restrict__ Op) {
    __shared__ ushort_t SMEM[33280];   // 8 buffers x 4160 ushorts = 66560 B
    __shared__ float sBias[1024];

    const int idx = blockIdx.x;
    const int bh_i = idx & 63;
    const int qc  = idx >> 6;          // 0..3
    const int b = bh_i >> 3, h = bh_i & 7;
    const size_t bh = (size_t)b * NH + h;

    const int tid   = threadIdx.x;
    const int wave  = tid >> 6;        // 0..15
    const int strip = wave >> 1;       // q-strip 0..7
    const int grp   = wave & 1;        // k-group 0..1
    const int lane  = tid & 63;
    const int l31   = lane & 31;
    const int hib   = lane >> 5;
    const int q = qc * 256 + strip * 32 + l31;
    const int sw = l31 & 7;

    // buffer layout: [grp][buf][K|V]
    auto sKp = [&](int g, int bf) { return SMEM + (g * 4 + bf * 2 + 0) * 4160; };
    auto sVp = [&](int g, int bf) { return SMEM + (g * 4 + bf * 2 + 1) * 4160; };

    // bias = mask ? -SHIFT2 : -1e30  (exp2-domain shift + mask in one constant)
    if (tid < 256) {
        const float* mrow = maskp + ((size_t)b << 10);
        float4 m0 = *(const float4*)&mrow[tid * 4];
        float4 bi;
        bi.x = (m0.x > 0.5f) ? -SHIFT2 : MASKV;
        bi.y = (m0.y > 0.5f) ? -SHIFT2 : MASKV;
        bi.z = (m0.z > 0.5f) ? -SHIFT2 : MASKV;
        bi.w = (m0.w > 0.5f) ? -SHIFT2 : MASKV;
        *(float4*)&sBias[tid * 4] = bi;
    }

    f16x8 qh[4];
    {
        const ushort_t* ph = Qf + (bh * NLQ + q) * 64 + hib * 8;
#pragma unroll
        for (int c = 0; c < 4; c++) qh[c] = *(const f16x8*)(ph + c * 16);
    }

    const int srow = lane >> 3;
    const int schk = (lane & 7) ^ srow;

    // K rows permuted (storage row s holds key swap23(s)); V natural; group-padded
    // 16 staging units per k-group spread over its 8 waves (2 each).
    auto stage = [&](int buf, int k0) {
#pragma unroll
        for (int n = 0; n < 2; n++) {
            int u = strip + n * 8;          // 0..15, uniform per wave
            if (u < 8) {
                int row = u * 8 + srow;
                int key = (row & ~12) | ((row & 4) << 1) | ((row & 8) >> 1);
                gload16(Kf + ((bh << 10) + k0 + key) * 64 + schk * 8,
                        sKp(grp, buf) + u * 520);
            } else {
                int u8 = u - 8;
                int row = u8 * 8 + srow;
                gload16(Vt + ((bh << 6) + row) * NLK + k0 + schk * 8,
                        sVp(grp, buf) + u8 * 520);
            }
        }
    };

    f32x16 O0, O1;
#pragma unroll
    for (int i = 0; i < 16; i++) { O0[i] = 0.f; O1[i] = 0.f; }
    float lrun = 0.f;

    const int rp0 = (l31 >> 3) * 520 + (l31 & 7) * 64;   // rows 0..31
    const int rp1 = rp0 + 4 * 520;                        // rows 32..63

    stage(0, grp * 512);
    __syncthreads();
    int cur = 0;

    for (int t = 0; t < 8; t++) {
        const int k0 = (grp * 8 + t) << 6;
        if (t < 7) stage(cur ^ 1, k0 + 64);

        // S init = bias (C-operand); quad g of half s holds keys
        // k0 + 32s + 16(g>>1) + 8hib + 4(g&1) + {0..3}
        f32x16 S0, S1;
#pragma unroll
        for (int g = 0; g < 4; g++) {
            const int kb = k0 + 16 * (g >> 1) + 8 * hib + 4 * (g & 1);
            float4 b0 = *(const float4*)&sBias[kb];
            float4 b1 = *(const float4*)&sBias[kb + 32];
            S0[4 * g + 0] = b0.x; S0[4 * g + 1] = b0.y;
            S0[4 * g + 2] = b0.z; S0[4 * g + 3] = b0.w;
            S1[4 * g + 0] = b1.x; S1[4 * g + 1] = b1.y;
            S1[4 * g + 2] = b1.z; S1[4 * g + 3] = b1.w;
        }
        __builtin_amdgcn_s_setprio(1);
#pragma unroll
        for (int c = 0; c < 4; c++) {
            const int pc = ((2 * c + hib) ^ sw) * 8;
            f16x8 a0 = *(const f16x8*)&sKp(grp, cur)[rp0 + pc];
            f16x8 a1 = *(const f16x8*)&sKp(grp, cur)[rp1 + pc];
            S0 = __builtin_amdgcn_mfma_f32_32x32x16_f16(a0, qh[c], S0, 0, 0, 0);
            S1 = __builtin_amdgcn_mfma_f32_32x32x16_f16(a1, qh[c], S1, 0, 0, 0);
        }
        __builtin_amdgcn_s_setprio(0);

        // p = exp2(S + bias); pack to bf16 (fp32 range -> no overflow, no max needed)
        unsigned pq[8][2];
#pragma unroll
        for (int g = 0; g < 8; g++) {
            float p0, p1, p2, p3;
            if (g < 4) {
                p0 = __builtin_amdgcn_exp2f(S0[4*g+0]);
                p1 = __builtin_amdgcn_exp2f(S0[4*g+1]);
                p2 = __builtin_amdgcn_exp2f(S0[4*g+2]);
                p3 = __builtin_amdgcn_exp2f(S0[4*g+3]);
            } else {
                p0 = __builtin_amdgcn_exp2f(S1[4*(g-4)+0]);
                p1 = __builtin_amdgcn_exp2f(S1[4*(g-4)+1]);
                p2 = __builtin_amdgcn_exp2f(S1[4*(g-4)+2]);
                p3 = __builtin_amdgcn_exp2f(S1[4*(g-4)+3]);
            }
            lrun += (p0 + p1) + (p2 + p3);
            pq[g][0] = pack_bf16_trunc(p0, p1);
            pq[g][1] = pack_bf16_trunc(p2, p3);
        }

        // O^T += V^T · P^T  (bf16; P fragment for chunk c = lane-local quads 2c,2c+1)
        __builtin_amdgcn_s_setprio(1);
#pragma unroll
        for (int c = 0; c < 4; c++) {
            union { unsigned u[4]; bf16x8 v; } pf;
            pf.u[0] = pq[2 * c][0];     pf.u[1] = pq[2 * c][1];
            pf.u[2] = pq[2 * c + 1][0]; pf.u[3] = pq[2 * c + 1][1];
            const int pc = ((2 * c + hib) ^ sw) * 8;
            bf16x8 v0 = *(const bf16x8*)&sVp(grp, cur)[rp0 + pc];
            bf16x8 v1 = *(const bf16x8*)&sVp(grp, cur)[rp1 + pc];
            O0 = __builtin_amdgcn_mfma_f32_32x32x16_bf16(v0, pf.v, O0, 0, 0, 0);
            O1 = __builtin_amdgcn_mfma_f32_32x32x16_bf16(v1, pf.v, O1, 0, 0, 0);
        }
        __builtin_amdgcn_s_setprio(0);
        __syncthreads();
        cur ^= 1;
    }

    // ---- cross-group combine (fixed-shift softmax: pure sums, no rescale)
    float* scr = (float*)SMEM;               // 66560 B >= 8 strips x 8 KB
    float* slr = (float*)sBias;              // lrun scratch (bias dead now)
    if (grp == 1) {
        float* basep = scr + strip * 2048;
#pragma unroll
        for (int i = 0; i < 16; i++) {
            basep[i * 64 + lane]        = O0[i];
            basep[(16 + i) * 64 + lane] = O1[i];
        }
        slr[strip * 64 + lane] = lrun;
    }
    __syncthreads();
    if (grp == 0) {
        float* basep = scr + strip * 2048;
#pragma unroll
        for (int i = 0; i < 16; i++) {
            O0[i] += basep[i * 64 + lane];
            O1[i] += basep[(16 + i) * 64 + lane];
        }
        lrun += slr[strip * 64 + lane];

        lrun += __shfl_xor(lrun, 32);     // other key-half lives in lane^32
        const float linv = 1.f / lrun;
        float* obase = Op + ((size_t)(b * NLQ + q)) * (NH * 64) + h * 64;
#pragma unroll
        for (int me = 0; me < 2; me++) {
#pragma unroll
            for (int g = 0; g < 4; g++) {
                int e0 = me * 32 + 8 * g + 4 * hib;
                float4 o;
                if (me == 0) {
                    o.x = O0[4 * g + 0] * linv; o.y = O0[4 * g + 1] * linv;
                    o.z = O0[4 * g + 2] * linv; o.w = O0[4 * g + 3] * linv;
                } else {
                    o.x = O1[4 * g + 0] * linv; o.y = O1[4 * g + 1] * linv;
                    o.z = O1[4 * g + 2] * linv; o.w = O1[4 * g + 3] * linv;
                }
                *(float4*)&obase[e0] = o;
            }
        }
    }
}

// ---------------- LayerNorm (unchanged).
__global__ __launch_bounds__(256) void ln_kernel(const float* __restrict__ X,
                                                 const float* __restrict__ gamma,
                                                 const float* __restrict__ beta,
                                                 float* __restrict__ out) {
    const int row = blockIdx.x * 4 + (threadIdx.x >> 6);
    const int lane = threadIdx.x & 63;
    const float* x = &X[(size_t)row * 512];
    float4 v0 = *(const float4*)&x[lane * 8];
    float4 v1 = *(const float4*)&x[lane * 8 + 4];
    float sum = v0.x + v0.y + v0.z + v0.w + v1.x + v1.y + v1.z + v1.w;
    float sq = v0.x * v0.x + v0.y * v0.y + v0.z * v0.z + v0.w * v0.w
             + v1.x * v1.x + v1.y * v1.y + v1.z * v1.z + v1.w * v1.w;
#pragma unroll
    for (int off = 32; off > 0; off >>= 1) {
        sum += __shfl_down(sum, off);
        sq  += __shfl_down(sq, off);
    }
    sum = __shfl(sum, 0);
    sq  = __shfl(sq, 0);
    const float mean = sum * (1.f / 512.f);
    const float var = sq * (1.f / 512.f) - mean * mean;
    const float rstd = rsqrtf(var + 1e-14f);
    const float g = gamma[0], be = beta[0];
    float* o = &out[(size_t)row * 512];
    float4 r0, r1;
    r0.x = (v0.x - mean) * rstd * g + be;  r0.y = (v0.y - mean) * rstd * g + be;
    r0.z = (v0.z - mean) * rstd * g + be;  r0.w = (v0.w - mean) * rstd * g + be;
    r1.x = (v1.x - mean) * rstd * g + be;  r1.y = (v1.y - mean) * rstd * g + be;
    r1.z = (v1.z - mean) * rstd * g + be;  r1.w = (v1.w - mean) * rstd * g + be;
    *(float4*)&o[lane * 8] = r0;
    *(float4*)&o[lane * 8 + 4] = r1;
}

extern "C" void kernel_launch(void* const* d_in, const int* in_sizes, int n_in,
                              void* d_out, int out_size, void* d_ws, size_t ws_size,
                              hipStream_t stream) {
    const float* query = (const float*)d_in[0];
    const float* key_t = (const float*)d_in[1];
    const float* value = (const float*)d_in[2];
    const float* mask  = (const float*)d_in[3];
    const float* Wq    = (const float*)d_in[4];
    const float* Wk    = (const float*)d_in[5];
    const float* Wv    = (const float*)d_in[6];
    const float* gamma = (const float*)d_in[7];
    const float* beta  = (const float*)d_in[8];
    float* out = (float*)d_out;

    const size_t A = (size_t)NB * NLQ * ND;        // 4,194,304 (= per-tensor size)
    const size_t WS = (size_t)NH * 64 * ND;        // 262,144
    ushort_t* Qf = (ushort_t*)d_ws;                // fp16 (b,h,l,64), *log2e
    ushort_t* Kf = Qf + A;                          // fp16 (b,h,l,64)
    ushort_t* Vt = Qf + 2 * A;                      // bf16 (b,h,e,l)
    ushort_t* Wt = Qf + 3 * A;                      // fp16 Wt, 3 tensors contiguous

    wsplit_kernel<<<dim3(ND / 64, NH, 3), 256, 0, stream>>>(
        Wq, Wk, Wv, Wt, Wt + WS, Wt + 2 * WS);

    proj_gemm_kernel<<<768, 256, 0, stream>>>(
        query, key_t, value, Wt, Qf);

    attn_kernel<<<256, 1024, 0, stream>>>(Qf, Kf, Vt, mask, out);

    ln_kernel<<<(NB * NLQ) / 4, 256, 0, stream>>>(out, gamma, beta, out);
}